// Round 1
// baseline (302.602 us; speedup 1.0000x reference)
//
#include <hip/hip_runtime.h>
#include <hip/hip_bf16.h>
#include <math.h>

#define BATCH 512
#define FEAT  256
#define NCLS  100000
#define SCALE_ 32.0f
#define M0_    0.5f
#define MMIN_  0.25f

#define BM 128
#define BN 128
#define NT ((NCLS + BN - 1) / BN)   // 782
#define MT (BATCH / BM)             // 4

typedef unsigned short u16;
typedef short s16x8 __attribute__((ext_vector_type(8)));
typedef float f32x4 __attribute__((ext_vector_type(4)));

// ---- static device scratch (avoids dependence on ws_size) ----
__device__ u16   g_wbf16[NCLS * FEAT];     // 51.2 MB bf16 weight
__device__ u16   g_fbf16[BATCH * FEAT];    // bf16 features
__device__ float g_invw[NCLS];
__device__ float g_invf[BATCH];
__device__ float g_norms[BATCH];
__device__ float g_margin[BATCH];
__device__ float g_cost[BATCH];
__device__ float g_pmax[NT * BATCH];
__device__ float g_psum[NT * BATCH];
__device__ int   g_lab64;

__device__ __forceinline__ u16 f2b(float x) {
  union { float f; unsigned u; } v; v.f = x;
  unsigned r = v.u + 0x7FFFu + ((v.u >> 16) & 1u);   // RNE
  return (u16)(r >> 16);
}

__device__ __forceinline__ void gld_lds16(const void* g, void* l) {
  __builtin_amdgcn_global_load_lds(
      (const __attribute__((address_space(1))) void*)g,
      (__attribute__((address_space(3))) void*)l, 16, 0, 0);
}

// K1a: per-row feature norm (f32) + bf16 conversion. One wave per row.
__global__ void k1a(const float* __restrict__ feat) {
  int wid = threadIdx.x >> 6, lane = threadIdx.x & 63;
  int row = blockIdx.x * 4 + wid;
  float4 f = ((const float4*)(feat + row * FEAT))[lane];
  float ss = f.x * f.x + f.y * f.y + f.z * f.z + f.w * f.w;
  #pragma unroll
  for (int d = 1; d < 64; d <<= 1) ss += __shfl_xor(ss, d, 64);
  ushort4 h;
  h.x = f2b(f.x); h.y = f2b(f.y); h.z = f2b(f.z); h.w = f2b(f.w);
  ((ushort4*)(g_fbf16 + row * FEAT))[lane] = h;
  if (lane == 0) g_norms[row] = sqrtf(ss);
}

// K1b: min/max of norms -> margins & inv feature norms; label-width detect.
__global__ void k1b(const int* __restrict__ labw) {
  int i = threadIdx.x;  // 512
  float n = g_norms[i];
  __shared__ float smin[512], smax[512];
  __shared__ int sor[512];
  smin[i] = n; smax[i] = n;
  sor[i] = (i < 256) ? ((labw[2 * i + 1] != 0) ? 1 : 0) : 0;
  __syncthreads();
  for (int st = 256; st > 0; st >>= 1) {
    if (i < st) {
      smin[i] = fminf(smin[i], smin[i + st]);
      smax[i] = fmaxf(smax[i], smax[i + st]);
      sor[i] |= sor[i + st];
    }
    __syncthreads();
  }
  float lo = smin[0], hi = smax[0];
  float denom = fmaxf(hi - lo, 1e-8f);
  float mg = MMIN_ + (M0_ - MMIN_) * (n - lo) / denom;
  mg = fminf(fmaxf(mg, MMIN_), M0_);
  g_margin[i] = mg;
  g_invf[i] = 1.0f / fmaxf(n, 1e-12f);
  if (i == 0) g_lab64 = (sor[0] == 0) ? 1 : 0;  // all odd int32 words zero => int64 labels
}

// K2: weight row norms (f32) + bf16 conversion. One wave per class row.
__global__ void k2(const float* __restrict__ wmat) {
  int wid = threadIdx.x >> 6, lane = threadIdx.x & 63;
  int row = blockIdx.x * 4 + wid;   // exact: 25000*4 = 100000
  float4 f = ((const float4*)(wmat + (size_t)row * FEAT))[lane];
  float ss = f.x * f.x + f.y * f.y + f.z * f.z + f.w * f.w;
  #pragma unroll
  for (int d = 1; d < 64; d <<= 1) ss += __shfl_xor(ss, d, 64);
  ushort4 h;
  h.x = f2b(f.x); h.y = f2b(f.y); h.z = f2b(f.z); h.w = f2b(f.w);
  ((ushort4*)(g_wbf16 + (size_t)row * FEAT))[lane] = h;
  if (lane == 0) g_invw[row] = 1.0f / fmaxf(sqrtf(ss), 1e-12f);
}

// K2c: f32 target cosine per sample. One wave per row.
__global__ void k2c(const float* __restrict__ feat, const float* __restrict__ wmat,
                    const void* __restrict__ labels) {
  int wid = threadIdx.x >> 6, lane = threadIdx.x & 63;
  int i = blockIdx.x * 4 + wid;
  long long lab;
  if (g_lab64) lab = ((const long long*)labels)[i];
  else         lab = (long long)((const int*)labels)[i];
  float4 a = ((const float4*)(feat + i * FEAT))[lane];
  float4 b = ((const float4*)(wmat + (size_t)lab * FEAT))[lane];
  float d = a.x * b.x + a.y * b.y + a.z * b.z + a.w * b.w;
  #pragma unroll
  for (int t = 1; t < 64; t <<= 1) d += __shfl_xor(d, t, 64);
  if (lane == 0) {
    float ct = d * g_invf[i] * g_invw[lab];
    const float CLIP = 1.0f - 1e-7f;
    ct = fminf(fmaxf(ct, -CLIP), CLIP);
    g_cost[i] = ct;
  }
}

// K3: 128x128 bf16 MFMA tile; online (max, sumexp) partials per row.
// LDS layout: [row][256 bf16] with 16B-chunk XOR swizzle c' = c ^ (row&7),
// achieved by pre-swizzling the GLOBAL source address (linear global_load_lds dest).
__global__ __launch_bounds__(512) void k3() {
  __shared__ __align__(16) u16 As[BM * FEAT];  // 64 KB
  __shared__ __align__(16) u16 Ws[BN * FEAT];  // 64 KB
  __shared__ float red_m[4][BM];
  __shared__ float red_s[4][BM];
  __shared__ float invf_s[BM];
  __shared__ float invw_s[BN];

  const int tid = threadIdx.x;
  const int mtile = blockIdx.x, ntile = blockIdx.y;

  if (tid < BM) {
    invf_s[tid] = g_invf[mtile * BM + tid];
  } else if (tid < BM + BN) {
    int j = ntile * BN + (tid - BM);
    invw_s[tid - BM] = (j < NCLS) ? g_invw[j] : 0.0f;
  }

  // stage A (features, bf16): 4096 16B chunks
  #pragma unroll
  for (int it = 0; it < 8; ++it) {
    int p = it * 512 + tid;
    int row = p >> 5, c = p & 31;
    int cs = c ^ (row & 7);
    gld_lds16(g_fbf16 + (mtile * BM + row) * FEAT + cs * 8, As + p * 8);
  }
  // stage W (classes, bf16)
  #pragma unroll
  for (int it = 0; it < 8; ++it) {
    int p = it * 512 + tid;
    int row = p >> 5, c = p & 31;
    int cs = c ^ (row & 7);
    int grow = ntile * BN + row;
    grow = grow < NCLS ? grow : NCLS - 1;
    gld_lds16(g_wbf16 + (size_t)grow * FEAT + cs * 8, Ws + p * 8);
  }
  __syncthreads();

  const int lane = tid & 63, wid = tid >> 6;
  const int wr = wid >> 2, wc = wid & 3;   // 2x4 waves; wave tile 64x32
  const int q = lane >> 4, s = lane & 15;

  f32x4 acc[4][2];
  #pragma unroll
  for (int m = 0; m < 4; ++m)
    #pragma unroll
    for (int n = 0; n < 2; ++n)
      acc[m][n] = f32x4{0.0f, 0.0f, 0.0f, 0.0f};

  #pragma unroll
  for (int ks = 0; ks < 8; ++ks) {
    const int chunk = ks * 4 + q;
    s16x8 a[4], b[2];
    #pragma unroll
    for (int m = 0; m < 4; ++m) {
      int row = wr * 64 + m * 16 + s;
      a[m] = *(const s16x8*)(As + row * FEAT + (chunk ^ (row & 7)) * 8);
    }
    #pragma unroll
    for (int n = 0; n < 2; ++n) {
      int row = wc * 32 + n * 16 + s;
      b[n] = *(const s16x8*)(Ws + row * FEAT + (chunk ^ (row & 7)) * 8);
    }
    #pragma unroll
    for (int m = 0; m < 4; ++m)
      #pragma unroll
      for (int n = 0; n < 2; ++n)
        acc[m][n] = __builtin_amdgcn_mfma_f32_16x16x32_bf16(a[m], b[n], acc[m][n], 0, 0, 0);
  }

  // epilogue: scale->clip->logit, per-row max & sumexp over this wave's 32 cols
  const float CLIP = 1.0f - 1e-7f;
  #pragma unroll
  for (int m = 0; m < 4; ++m) {
    #pragma unroll
    for (int r = 0; r < 4; ++r) {
      int rowl = wr * 64 + m * 16 + q * 4 + r;
      float invf = invf_s[rowl];
      float v0, v1;
      {
        int coll = wc * 32 + s;
        float cs_ = acc[m][0][r] * invf * invw_s[coll];
        cs_ = fminf(fmaxf(cs_, -CLIP), CLIP);
        v0 = ((ntile * BN + coll) < NCLS) ? SCALE_ * cs_ : -1e30f;
      }
      {
        int coll = wc * 32 + 16 + s;
        float cs_ = acc[m][1][r] * invf * invw_s[coll];
        cs_ = fminf(fmaxf(cs_, -CLIP), CLIP);
        v1 = ((ntile * BN + coll) < NCLS) ? SCALE_ * cs_ : -1e30f;
      }
      float mx = fmaxf(v0, v1);
      #pragma unroll
      for (int d = 1; d < 16; d <<= 1) mx = fmaxf(mx, __shfl_xor(mx, d, 64));
      float sm = __expf(v0 - mx) + __expf(v1 - mx);
      #pragma unroll
      for (int d = 1; d < 16; d <<= 1) sm += __shfl_xor(sm, d, 64);
      if (s == 0) { red_m[wc][rowl] = mx; red_s[wc][rowl] = sm; }
    }
  }
  __syncthreads();

  if (tid < BM) {
    float M = -1e30f, S = 0.0f;
    #pragma unroll
    for (int w = 0; w < 4; ++w) {
      float m2 = red_m[w][tid], s2 = red_s[w][tid];
      float nM = fmaxf(M, m2);
      S = S * __expf(M - nM) + s2 * __expf(m2 - nM);
      M = nM;
    }
    g_pmax[ntile * BATCH + mtile * BM + tid] = M;
    g_psum[ntile * BATCH + mtile * BM + tid] = S;
  }
}

// K4: combine tile partials per row, margin-adjust label term, weighted mean.
__global__ void k4(const float* __restrict__ wts, float* __restrict__ out) {
  int i = threadIdx.x;  // 512
  float M = -1e30f, S = 0.0f;
  for (int t = 0; t < NT; ++t) {
    float m2 = g_pmax[t * BATCH + i];
    float s2 = g_psum[t * BATCH + i];
    float nM = fmaxf(M, m2);
    S = S * __expf(M - nM) + s2 * __expf(m2 - nM);
    M = nM;
  }
  float ct = g_cost[i];
  float mg = g_margin[i];
  float sint = sqrtf(fmaxf(0.0f, 1.0f - ct * ct));
  float cosm = ct * cosf(mg) - sint * sinf(mg);
  float lt_old = SCALE_ * ct, lt_new = SCALE_ * cosm;
  float S2 = S - __expf(lt_old - M) + __expf(lt_new - M);
  float lse = M + logf(S2);
  float contrib = (lse - lt_new) * wts[i];
  __shared__ float sred[512];
  sred[i] = contrib;
  __syncthreads();
  for (int st = 256; st > 0; st >>= 1) {
    if (i < st) sred[i] += sred[i + st];
    __syncthreads();
  }
  if (i == 0) out[0] = sred[0] * (1.0f / (float)BATCH);
}

extern "C" void kernel_launch(void* const* d_in, const int* in_sizes, int n_in,
                              void* d_out, int out_size, void* d_ws, size_t ws_size,
                              hipStream_t stream) {
  const float* feat = (const float*)d_in[0];
  const float* wmat = (const float*)d_in[1];
  const float* wts  = (const float*)d_in[2];
  const void*  labs = d_in[3];
  float* out = (float*)d_out;

  hipLaunchKernelGGL(k1a, dim3(BATCH / 4), dim3(256), 0, stream, feat);
  hipLaunchKernelGGL(k1b, dim3(1), dim3(512), 0, stream, (const int*)labs);
  hipLaunchKernelGGL(k2,  dim3(NCLS / 4), dim3(256), 0, stream, wmat);
  hipLaunchKernelGGL(k2c, dim3(BATCH / 4), dim3(256), 0, stream, feat, wmat, labs);
  hipLaunchKernelGGL(k3,  dim3(MT, NT), dim3(512), 0, stream);
  hipLaunchKernelGGL(k4,  dim3(1), dim3(512), 0, stream, wts, out);
}

// Round 2
// 176.618 us; speedup vs baseline: 1.7133x; 1.7133x over previous
//
#include <hip/hip_runtime.h>
#include <hip/hip_bf16.h>
#include <math.h>

#define BATCH 512
#define FEAT  256
#define NCLS  100000
#define SCALE_ 32.0f
#define M0_    0.5f
#define MMIN_  0.25f

#define BM 128
#define BN 128
#define NT ((NCLS + BN - 1) / BN)   // 782
#define MT (BATCH / BM)             // 4
#define CHUNK 16
#define NCHUNK ((NT + CHUNK - 1) / CHUNK)  // 49

typedef unsigned short u16;
typedef short s16x8 __attribute__((ext_vector_type(8)));
typedef float f32x4 __attribute__((ext_vector_type(4)));

// ---- static device scratch (avoids dependence on ws_size) ----
__device__ u16   g_wbf16[NCLS * FEAT];     // 51.2 MB bf16 weight
__device__ u16   g_fbf16[BATCH * FEAT];    // bf16 features
__device__ float g_invw[NCLS];
__device__ float g_invf[BATCH];
__device__ float g_norms[BATCH];
__device__ float g_margin[BATCH];
__device__ float g_cost[BATCH];
__device__ float g_pmax[NT * BATCH];
__device__ float g_psum[NT * BATCH];
__device__ float g_qm[NCHUNK * BATCH];
__device__ float g_qs[NCHUNK * BATCH];
__device__ int   g_lab64;

__device__ __forceinline__ u16 f2b(float x) {
  union { float f; unsigned u; } v; v.f = x;
  unsigned r = v.u + 0x7FFFu + ((v.u >> 16) & 1u);   // RNE
  return (u16)(r >> 16);
}

__device__ __forceinline__ void gld_lds16(const void* g, void* l) {
  __builtin_amdgcn_global_load_lds(
      (const __attribute__((address_space(1))) void*)g,
      (__attribute__((address_space(3))) void*)l, 16, 0, 0);
}

// K1a: per-row feature norm (f32) + bf16 conversion. One wave per row.
__global__ void k1a(const float* __restrict__ feat) {
  int wid = threadIdx.x >> 6, lane = threadIdx.x & 63;
  int row = blockIdx.x * 4 + wid;
  float4 f = ((const float4*)(feat + row * FEAT))[lane];
  float ss = f.x * f.x + f.y * f.y + f.z * f.z + f.w * f.w;
  #pragma unroll
  for (int d = 1; d < 64; d <<= 1) ss += __shfl_xor(ss, d, 64);
  ushort4 h;
  h.x = f2b(f.x); h.y = f2b(f.y); h.z = f2b(f.z); h.w = f2b(f.w);
  ((ushort4*)(g_fbf16 + row * FEAT))[lane] = h;
  if (lane == 0) g_norms[row] = sqrtf(ss);
}

// K1b: min/max of norms -> margins & inv feature norms; label-width detect.
__global__ void k1b(const int* __restrict__ labw) {
  int i = threadIdx.x;  // 512
  float n = g_norms[i];
  __shared__ float smin[512], smax[512];
  __shared__ int sor[512];
  smin[i] = n; smax[i] = n;
  sor[i] = (i < 256) ? ((labw[2 * i + 1] != 0) ? 1 : 0) : 0;
  __syncthreads();
  for (int st = 256; st > 0; st >>= 1) {
    if (i < st) {
      smin[i] = fminf(smin[i], smin[i + st]);
      smax[i] = fmaxf(smax[i], smax[i + st]);
      sor[i] |= sor[i + st];
    }
    __syncthreads();
  }
  float lo = smin[0], hi = smax[0];
  float denom = fmaxf(hi - lo, 1e-8f);
  float mg = MMIN_ + (M0_ - MMIN_) * (n - lo) / denom;
  mg = fminf(fmaxf(mg, MMIN_), M0_);
  g_margin[i] = mg;
  g_invf[i] = 1.0f / fmaxf(n, 1e-12f);
  if (i == 0) g_lab64 = (sor[0] == 0) ? 1 : 0;  // all odd int32 words zero => int64 labels
}

// K2: weight row norms (f32) + bf16 conversion. One wave per class row.
__global__ void k2(const float* __restrict__ wmat) {
  int wid = threadIdx.x >> 6, lane = threadIdx.x & 63;
  int row = blockIdx.x * 4 + wid;   // exact: 25000*4 = 100000
  float4 f = ((const float4*)(wmat + (size_t)row * FEAT))[lane];
  float ss = f.x * f.x + f.y * f.y + f.z * f.z + f.w * f.w;
  #pragma unroll
  for (int d = 1; d < 64; d <<= 1) ss += __shfl_xor(ss, d, 64);
  ushort4 h;
  h.x = f2b(f.x); h.y = f2b(f.y); h.z = f2b(f.z); h.w = f2b(f.w);
  ((ushort4*)(g_wbf16 + (size_t)row * FEAT))[lane] = h;
  if (lane == 0) g_invw[row] = 1.0f / fmaxf(sqrtf(ss), 1e-12f);
}

// K2c: f32 target cosine per sample. One wave per row.
__global__ void k2c(const float* __restrict__ feat, const float* __restrict__ wmat,
                    const void* __restrict__ labels) {
  int wid = threadIdx.x >> 6, lane = threadIdx.x & 63;
  int i = blockIdx.x * 4 + wid;
  long long lab;
  if (g_lab64) lab = ((const long long*)labels)[i];
  else         lab = (long long)((const int*)labels)[i];
  float4 a = ((const float4*)(feat + i * FEAT))[lane];
  float4 b = ((const float4*)(wmat + (size_t)lab * FEAT))[lane];
  float d = a.x * b.x + a.y * b.y + a.z * b.z + a.w * b.w;
  #pragma unroll
  for (int t = 1; t < 64; t <<= 1) d += __shfl_xor(d, t, 64);
  if (lane == 0) {
    float ct = d * g_invf[i] * g_invw[lab];
    const float CLIP = 1.0f - 1e-7f;
    ct = fminf(fmaxf(ct, -CLIP), CLIP);
    g_cost[i] = ct;
  }
}

// K3: 128x128 bf16 MFMA tile; online (max, sumexp) partials per row.
// LDS layout: [row][256 bf16] with 16B-chunk XOR swizzle c' = c ^ (row&7),
// achieved by pre-swizzling the GLOBAL source address (linear global_load_lds dest).
__global__ __launch_bounds__(512) void k3() {
  __shared__ __align__(16) u16 As[BM * FEAT];  // 64 KB
  __shared__ __align__(16) u16 Ws[BN * FEAT];  // 64 KB
  __shared__ float red_m[4][BM];
  __shared__ float red_s[4][BM];
  __shared__ float invf_s[BM];
  __shared__ float invw_s[BN];

  const int tid = threadIdx.x;
  const int mtile = blockIdx.x, ntile = blockIdx.y;

  if (tid < BM) {
    invf_s[tid] = g_invf[mtile * BM + tid];
  } else if (tid < BM + BN) {
    int j = ntile * BN + (tid - BM);
    invw_s[tid - BM] = (j < NCLS) ? g_invw[j] : 0.0f;
  }

  // stage A (features, bf16): 4096 16B chunks
  #pragma unroll
  for (int it = 0; it < 8; ++it) {
    int p = it * 512 + tid;
    int row = p >> 5, c = p & 31;
    int cs = c ^ (row & 7);
    gld_lds16(g_fbf16 + (mtile * BM + row) * FEAT + cs * 8, As + p * 8);
  }
  // stage W (classes, bf16)
  #pragma unroll
  for (int it = 0; it < 8; ++it) {
    int p = it * 512 + tid;
    int row = p >> 5, c = p & 31;
    int cs = c ^ (row & 7);
    int grow = ntile * BN + row;
    grow = grow < NCLS ? grow : NCLS - 1;
    gld_lds16(g_wbf16 + (size_t)grow * FEAT + cs * 8, Ws + p * 8);
  }
  __syncthreads();

  const int lane = tid & 63, wid = tid >> 6;
  const int wr = wid >> 2, wc = wid & 3;   // 2x4 waves; wave tile 64x32
  const int q = lane >> 4, s = lane & 15;

  f32x4 acc[4][2];
  #pragma unroll
  for (int m = 0; m < 4; ++m)
    #pragma unroll
    for (int n = 0; n < 2; ++n)
      acc[m][n] = f32x4{0.0f, 0.0f, 0.0f, 0.0f};

  #pragma unroll
  for (int ks = 0; ks < 8; ++ks) {
    const int chunk = ks * 4 + q;
    s16x8 a[4], b[2];
    #pragma unroll
    for (int m = 0; m < 4; ++m) {
      int row = wr * 64 + m * 16 + s;
      a[m] = *(const s16x8*)(As + row * FEAT + (chunk ^ (row & 7)) * 8);
    }
    #pragma unroll
    for (int n = 0; n < 2; ++n) {
      int row = wc * 32 + n * 16 + s;
      b[n] = *(const s16x8*)(Ws + row * FEAT + (chunk ^ (row & 7)) * 8);
    }
    #pragma unroll
    for (int m = 0; m < 4; ++m)
      #pragma unroll
      for (int n = 0; n < 2; ++n)
        acc[m][n] = __builtin_amdgcn_mfma_f32_16x16x32_bf16(a[m], b[n], acc[m][n], 0, 0, 0);
  }

  // epilogue: scale->clip->logit, per-row max & sumexp over this wave's 32 cols
  const float CLIP = 1.0f - 1e-7f;
  #pragma unroll
  for (int m = 0; m < 4; ++m) {
    #pragma unroll
    for (int r = 0; r < 4; ++r) {
      int rowl = wr * 64 + m * 16 + q * 4 + r;
      float invf = invf_s[rowl];
      float v0, v1;
      {
        int coll = wc * 32 + s;
        float cs_ = acc[m][0][r] * invf * invw_s[coll];
        cs_ = fminf(fmaxf(cs_, -CLIP), CLIP);
        v0 = ((ntile * BN + coll) < NCLS) ? SCALE_ * cs_ : -1e30f;
      }
      {
        int coll = wc * 32 + 16 + s;
        float cs_ = acc[m][1][r] * invf * invw_s[coll];
        cs_ = fminf(fmaxf(cs_, -CLIP), CLIP);
        v1 = ((ntile * BN + coll) < NCLS) ? SCALE_ * cs_ : -1e30f;
      }
      float mx = fmaxf(v0, v1);
      #pragma unroll
      for (int d = 1; d < 16; d <<= 1) mx = fmaxf(mx, __shfl_xor(mx, d, 64));
      float sm = __expf(v0 - mx) + __expf(v1 - mx);
      #pragma unroll
      for (int d = 1; d < 16; d <<= 1) sm += __shfl_xor(sm, d, 64);
      if (s == 0) { red_m[wc][rowl] = mx; red_s[wc][rowl] = sm; }
    }
  }
  __syncthreads();

  if (tid < BM) {
    float M = -1e30f, S = 0.0f;
    #pragma unroll
    for (int w = 0; w < 4; ++w) {
      float m2 = red_m[w][tid], s2 = red_s[w][tid];
      float nM = fmaxf(M, m2);
      S = S * __expf(M - nM) + s2 * __expf(m2 - nM);
      M = nM;
    }
    g_pmax[ntile * BATCH + mtile * BM + tid] = M;
    g_psum[ntile * BATCH + mtile * BM + tid] = S;
  }
}

// K4a: parallel chunk-combine of tile partials. Block b combines tiles
// [b*CHUNK, b*CHUNK+CHUNK) for all 512 rows (coalesced reads).
__global__ __launch_bounds__(512) void k4a() {
  int i = threadIdx.x;           // row
  int b = blockIdx.x;            // chunk
  int t0 = b * CHUNK;
  int t1 = t0 + CHUNK; if (t1 > NT) t1 = NT;
  float M = -1e30f, S = 0.0f;
  for (int t = t0; t < t1; ++t) {
    float m2 = g_pmax[t * BATCH + i];
    float s2 = g_psum[t * BATCH + i];
    float nM = fmaxf(M, m2);
    S = S * __expf(M - nM) + s2 * __expf(m2 - nM);
    M = nM;
  }
  g_qm[b * BATCH + i] = M;
  g_qs[b * BATCH + i] = S;
}

// K4b: combine chunk partials per row, margin-adjust label term, weighted mean.
__global__ void k4b(const float* __restrict__ wts, float* __restrict__ out) {
  int i = threadIdx.x;  // 512
  float M = -1e30f, S = 0.0f;
  #pragma unroll 7
  for (int t = 0; t < NCHUNK; ++t) {
    float m2 = g_qm[t * BATCH + i];
    float s2 = g_qs[t * BATCH + i];
    float nM = fmaxf(M, m2);
    S = S * __expf(M - nM) + s2 * __expf(m2 - nM);
    M = nM;
  }
  float ct = g_cost[i];
  float mg = g_margin[i];
  float sint = sqrtf(fmaxf(0.0f, 1.0f - ct * ct));
  float cosm = ct * cosf(mg) - sint * sinf(mg);
  float lt_old = SCALE_ * ct, lt_new = SCALE_ * cosm;
  float S2 = S - __expf(lt_old - M) + __expf(lt_new - M);
  float lse = M + logf(S2);
  float contrib = (lse - lt_new) * wts[i];
  __shared__ float sred[512];
  sred[i] = contrib;
  __syncthreads();
  for (int st = 256; st > 0; st >>= 1) {
    if (i < st) sred[i] += sred[i + st];
    __syncthreads();
  }
  if (i == 0) out[0] = sred[0] * (1.0f / (float)BATCH);
}

extern "C" void kernel_launch(void* const* d_in, const int* in_sizes, int n_in,
                              void* d_out, int out_size, void* d_ws, size_t ws_size,
                              hipStream_t stream) {
  const float* feat = (const float*)d_in[0];
  const float* wmat = (const float*)d_in[1];
  const float* wts  = (const float*)d_in[2];
  const void*  labs = d_in[3];
  float* out = (float*)d_out;

  hipLaunchKernelGGL(k1a, dim3(BATCH / 4), dim3(256), 0, stream, feat);
  hipLaunchKernelGGL(k1b, dim3(1), dim3(512), 0, stream, (const int*)labs);
  hipLaunchKernelGGL(k2,  dim3(NCLS / 4), dim3(256), 0, stream, wmat);
  hipLaunchKernelGGL(k2c, dim3(BATCH / 4), dim3(256), 0, stream, feat, wmat, labs);
  hipLaunchKernelGGL(k3,  dim3(MT, NT), dim3(512), 0, stream);
  hipLaunchKernelGGL(k4a, dim3(NCHUNK), dim3(512), 0, stream);
  hipLaunchKernelGGL(k4b, dim3(1), dim3(512), 0, stream, wts, out);
}

// Round 3
// 84.959 us; speedup vs baseline: 3.5618x; 2.0789x over previous
//
#include <hip/hip_runtime.h>
#include <hip/hip_bf16.h>
#include <math.h>

#define BATCH 512
#define FEAT  256
#define NCLS  100000
#define SCALE_ 32.0f
#define M0_    0.5f
#define MMIN_  0.25f

#define BN 128                       // classes per tile
#define NT 782                       // ceil(100000/128)
#define NSLOT 64                     // class-tile strides per mtile
#define NPART 256                    // partial slots per sample = NSLOT*4 wcls
#define K4CHUNK 16
#define NK4 (NPART / K4CHUNK)        // 16

typedef unsigned short u16;
typedef short s16x8 __attribute__((ext_vector_type(8)));
typedef float f32x4 __attribute__((ext_vector_type(4)));

// ---- static device scratch ----
__device__ u16   g_wbf16[NCLS * FEAT];     // normalized W rows, bf16
__device__ u16   g_fbf16[BATCH * FEAT];    // normalized features, bf16
__device__ float g_invw[NCLS];
__device__ float g_invf[BATCH];
__device__ float g_norms[BATCH];
__device__ float g_margin[BATCH];
__device__ float g_cost[BATCH];
__device__ float g_pmax[NPART * BATCH];
__device__ float g_psum[NPART * BATCH];
__device__ float g_qm[NK4 * BATCH];
__device__ float g_qs[NK4 * BATCH];
__device__ int   g_lab64;

__device__ __forceinline__ u16 f2b(float x) {
  union { float f; unsigned u; } v; v.f = x;
  unsigned r = v.u + 0x7FFFu + ((v.u >> 16) & 1u);   // RNE
  return (u16)(r >> 16);
}

__device__ __forceinline__ void gld_lds16(const void* g, void* l) {
  __builtin_amdgcn_global_load_lds(
      (const __attribute__((address_space(1))) void*)g,
      (__attribute__((address_space(3))) void*)l, 16, 0, 0);
}

// K1a: per-row feature norm; store NORMALIZED bf16 row. One wave per row.
__global__ void k1a(const float* __restrict__ feat) {
  int wid = threadIdx.x >> 6, lane = threadIdx.x & 63;
  int row = blockIdx.x * 4 + wid;
  float4 f = ((const float4*)(feat + row * FEAT))[lane];
  float ss = f.x * f.x + f.y * f.y + f.z * f.z + f.w * f.w;
  #pragma unroll
  for (int d = 1; d < 64; d <<= 1) ss += __shfl_xor(ss, d, 64);
  float nrm = sqrtf(ss);
  float inv = 1.0f / fmaxf(nrm, 1e-12f);
  ushort4 h;
  h.x = f2b(f.x * inv); h.y = f2b(f.y * inv);
  h.z = f2b(f.z * inv); h.w = f2b(f.w * inv);
  ((ushort4*)(g_fbf16 + row * FEAT))[lane] = h;
  if (lane == 0) g_norms[row] = nrm;
}

// K1b: min/max of norms -> margins & inv feature norms; label-width detect.
__global__ void k1b(const int* __restrict__ labw) {
  int i = threadIdx.x;  // 512
  float n = g_norms[i];
  __shared__ float smin[512], smax[512];
  __shared__ int sor[512];
  smin[i] = n; smax[i] = n;
  sor[i] = (i < 256) ? ((labw[2 * i + 1] != 0) ? 1 : 0) : 0;
  __syncthreads();
  for (int st = 256; st > 0; st >>= 1) {
    if (i < st) {
      smin[i] = fminf(smin[i], smin[i + st]);
      smax[i] = fmaxf(smax[i], smax[i + st]);
      sor[i] |= sor[i + st];
    }
    __syncthreads();
  }
  float lo = smin[0], hi = smax[0];
  float denom = fmaxf(hi - lo, 1e-8f);
  float mg = MMIN_ + (M0_ - MMIN_) * (n - lo) / denom;
  mg = fminf(fmaxf(mg, MMIN_), M0_);
  g_margin[i] = mg;
  g_invf[i] = 1.0f / fmaxf(n, 1e-12f);
  if (i == 0) g_lab64 = (sor[0] == 0) ? 1 : 0;
}

// K2: weight row norm; store NORMALIZED bf16 row + invw. One wave per class.
__global__ void k2(const float* __restrict__ wmat) {
  int wid = threadIdx.x >> 6, lane = threadIdx.x & 63;
  int row = blockIdx.x * 4 + wid;   // 25000*4 = 100000
  float4 f = ((const float4*)(wmat + (size_t)row * FEAT))[lane];
  float ss = f.x * f.x + f.y * f.y + f.z * f.z + f.w * f.w;
  #pragma unroll
  for (int d = 1; d < 64; d <<= 1) ss += __shfl_xor(ss, d, 64);
  float inv = 1.0f / fmaxf(sqrtf(ss), 1e-12f);
  ushort4 h;
  h.x = f2b(f.x * inv); h.y = f2b(f.y * inv);
  h.z = f2b(f.z * inv); h.w = f2b(f.w * inv);
  ((ushort4*)(g_wbf16 + (size_t)row * FEAT))[lane] = h;
  if (lane == 0) g_invw[row] = inv;
}

// K2c: f32 target cosine per sample (raw f32 inputs + f32 norms). One wave/row.
__global__ void k2c(const float* __restrict__ feat, const float* __restrict__ wmat,
                    const void* __restrict__ labels) {
  int wid = threadIdx.x >> 6, lane = threadIdx.x & 63;
  int i = blockIdx.x * 4 + wid;
  long long lab;
  if (g_lab64) lab = ((const long long*)labels)[i];
  else         lab = (long long)((const int*)labels)[i];
  float4 a = ((const float4*)(feat + i * FEAT))[lane];
  float4 b = ((const float4*)(wmat + (size_t)lab * FEAT))[lane];
  float d = a.x * b.x + a.y * b.y + a.z * b.z + a.w * b.w;
  #pragma unroll
  for (int t = 1; t < 64; t <<= 1) d += __shfl_xor(d, t, 64);
  if (lane == 0) {
    float ct = d * g_invf[i] * g_invw[lab];
    const float CLIP = 1.0f - 1e-7f;
    ct = fminf(fmaxf(ct, -CLIP), CLIP);
    g_cost[i] = ct;
  }
}

// K3: persistent blocks (1/CU). Each block: mtile (128 samples, A in regs) x
// nslot (class tiles nslot, nslot+64, ...). W double-buffered in LDS via
// global_load_lds with XOR-swizzled source; 2-phase pipeline with raw
// barriers + vmcnt(0) at end of iteration (catalog T3 minimum recipe).
// MFMA operands SWAPPED (D row=class, col=sample) so the softmax reduction
// is in-lane tree + 2 shfl steps; running (M,S) kept in registers.
#define STAGE(BUF, TILE) do {                                              \
    int cb_ = (TILE) * BN;                                                 \
    _Pragma("unroll")                                                      \
    for (int it_ = 0; it_ < 8; ++it_) {                                    \
      int p_ = it_ * 512 + tid;                                            \
      int row_ = p_ >> 5, cc_ = p_ & 31;                                   \
      int cs_ = cc_ ^ (row_ & 7);                                          \
      int grow_ = cb_ + row_; grow_ = grow_ < NCLS ? grow_ : NCLS - 1;     \
      gld_lds16(g_wbf16 + (size_t)grow_ * FEAT + cs_ * 8,                  \
                &Ws[BUF][0] + p_ * 8);                                     \
    }                                                                      \
  } while (0)

__global__ __launch_bounds__(512) void k3() {
  __shared__ __align__(16) u16 Ws[2][BN * FEAT];   // 2 x 64 KB

  const int tid  = threadIdx.x;
  const int lane = tid & 63, wid = tid >> 6;
  const int wsmp = wid >> 2;          // 0..1 : 64-sample group
  const int wcls = wid & 3;           // 0..3 : 32-class group
  const int bid = blockIdx.x;
  const int mtile = bid >> 6;         // 0..3
  const int nslot = bid & 63;         // 0..63
  const int niter = (NT - nslot + NSLOT - 1) / NSLOT;   // 13 (nslot<14) or 12
  const int s = lane & 15, q = lane >> 4;

  // prologue: stage tile 0
  STAGE(0, nslot);

  // feature fragments, held in registers for the whole loop.
  // fr[m][c]: sample = mtile*128 + wsmp*64 + m*16 + s ; k = c*32 + q*8
  s16x8 fr[4][8];
  {
    const int srow = mtile * 128 + wsmp * 64;
    #pragma unroll
    for (int m = 0; m < 4; ++m)
      #pragma unroll
      for (int c = 0; c < 8; ++c)
        fr[m][c] = *(const s16x8*)(g_fbf16 + (srow + m * 16 + s) * FEAT + c * 32 + q * 8);
  }

  float M[4], S[4];
  #pragma unroll
  for (int m = 0; m < 4; ++m) { M[m] = -1e30f; S[m] = 0.0f; }

  asm volatile("s_waitcnt vmcnt(0)");
  __builtin_amdgcn_s_barrier();

  int buf = 0;
  for (int t = 0; t < niter; ++t) {
    const int tile = nslot + t * NSLOT;
    if (t + 1 < niter) STAGE(buf ^ 1, nslot + (t + 1) * NSLOT);

    f32x4 acc[2][4];
    #pragma unroll
    for (int cf = 0; cf < 2; ++cf)
      #pragma unroll
      for (int m = 0; m < 4; ++m)
        acc[cf][m] = f32x4{0.0f, 0.0f, 0.0f, 0.0f};

    const u16* wb = &Ws[buf][0];
    #pragma unroll
    for (int c = 0; c < 8; ++c) {
      s16x8 wf[2];
      #pragma unroll
      for (int cf = 0; cf < 2; ++cf) {
        int row = wcls * 32 + cf * 16 + s;
        int cc = c * 4 + q;
        wf[cf] = *(const s16x8*)(wb + row * FEAT + (cc ^ (row & 7)) * 8);
      }
      #pragma unroll
      for (int cf = 0; cf < 2; ++cf)
        #pragma unroll
        for (int m = 0; m < 4; ++m)
          acc[cf][m] = __builtin_amdgcn_mfma_f32_16x16x32_bf16(wf[cf], fr[m][c], acc[cf][m], 0, 0, 0);
    }

    // epilogue: per smp-frag, online (max, sumexp) over this wave's 32 classes
    const int cbase = tile * BN + wcls * 32;
    const bool edge = (tile * BN + BN > NCLS);
    const float CLIP = 1.0f - 1e-7f;
    #pragma unroll
    for (int m = 0; m < 4; ++m) {
      float v[8];
      #pragma unroll
      for (int cf = 0; cf < 2; ++cf)
        #pragma unroll
        for (int r = 0; r < 4; ++r) {
          float cs_ = fminf(fmaxf(acc[cf][m][r], -CLIP), CLIP);
          float lv = SCALE_ * cs_;
          if (edge) {
            int cls = cbase + cf * 16 + q * 4 + r;
            if (cls >= NCLS) lv = -1e30f;
          }
          v[cf * 4 + r] = lv;
        }
      float mx = fmaxf(fmaxf(fmaxf(v[0], v[1]), fmaxf(v[2], v[3])),
                       fmaxf(fmaxf(v[4], v[5]), fmaxf(v[6], v[7])));
      mx = fmaxf(mx, __shfl_xor(mx, 16, 64));
      mx = fmaxf(mx, __shfl_xor(mx, 32, 64));
      float nM = fmaxf(M[m], mx);
      float sl = 0.0f;
      #pragma unroll
      for (int j = 0; j < 8; ++j) sl += __expf(v[j] - nM);
      sl += __shfl_xor(sl, 16, 64);
      sl += __shfl_xor(sl, 32, 64);
      S[m] = S[m] * __expf(M[m] - nM) + sl;
      M[m] = nM;
    }

    asm volatile("s_waitcnt vmcnt(0)");
    __builtin_amdgcn_s_barrier();
    buf ^= 1;
  }

  // write per-(sample, wcls, nslot) partials; all lanes hold full values,
  // lanes 0..15 write (coalesced over 16 consecutive samples).
  if (lane < 16) {
    int pslot = nslot * 4 + wcls;
    #pragma unroll
    for (int m = 0; m < 4; ++m) {
      int smp = mtile * 128 + wsmp * 64 + m * 16 + lane;
      g_pmax[pslot * BATCH + smp] = M[m];
      g_psum[pslot * BATCH + smp] = S[m];
    }
  }
}

// K4a: combine 16 of the 256 partials per sample per block (coalesced).
__global__ __launch_bounds__(512) void k4a() {
  int i = threadIdx.x;   // sample
  int b = blockIdx.x;    // chunk of partial slots
  float M = -1e30f, S = 0.0f;
  #pragma unroll 4
  for (int p = b * K4CHUNK; p < b * K4CHUNK + K4CHUNK; ++p) {
    float m2 = g_pmax[p * BATCH + i];
    float s2 = g_psum[p * BATCH + i];
    float nM = fmaxf(M, m2);
    S = S * __expf(M - nM) + s2 * __expf(m2 - nM);
    M = nM;
  }
  g_qm[b * BATCH + i] = M;
  g_qs[b * BATCH + i] = S;
}

// K4b: combine chunk partials, margin-adjust label term, weighted mean.
__global__ void k4b(const float* __restrict__ wts, float* __restrict__ out) {
  int i = threadIdx.x;  // 512
  float M = -1e30f, S = 0.0f;
  #pragma unroll
  for (int t = 0; t < NK4; ++t) {
    float m2 = g_qm[t * BATCH + i];
    float s2 = g_qs[t * BATCH + i];
    float nM = fmaxf(M, m2);
    S = S * __expf(M - nM) + s2 * __expf(m2 - nM);
    M = nM;
  }
  float ct = g_cost[i];
  float mg = g_margin[i];
  float sint = sqrtf(fmaxf(0.0f, 1.0f - ct * ct));
  float cosm = ct * cosf(mg) - sint * sinf(mg);
  float lt_old = SCALE_ * ct, lt_new = SCALE_ * cosm;
  float S2 = S - __expf(lt_old - M) + __expf(lt_new - M);
  float lse = M + logf(S2);
  float contrib = (lse - lt_new) * wts[i];
  __shared__ float sred[512];
  sred[i] = contrib;
  __syncthreads();
  for (int st = 256; st > 0; st >>= 1) {
    if (i < st) sred[i] += sred[i + st];
    __syncthreads();
  }
  if (i == 0) out[0] = sred[0] * (1.0f / (float)BATCH);
}

extern "C" void kernel_launch(void* const* d_in, const int* in_sizes, int n_in,
                              void* d_out, int out_size, void* d_ws, size_t ws_size,
                              hipStream_t stream) {
  const float* feat = (const float*)d_in[0];
  const float* wmat = (const float*)d_in[1];
  const float* wts  = (const float*)d_in[2];
  const void*  labs = d_in[3];
  float* out = (float*)d_out;

  hipLaunchKernelGGL(k1a, dim3(BATCH / 4), dim3(256), 0, stream, feat);
  hipLaunchKernelGGL(k1b, dim3(1), dim3(512), 0, stream, (const int*)labs);
  hipLaunchKernelGGL(k2,  dim3(NCLS / 4), dim3(256), 0, stream, wmat);
  hipLaunchKernelGGL(k2c, dim3(BATCH / 4), dim3(256), 0, stream, feat, wmat, labs);
  hipLaunchKernelGGL(k3,  dim3(256), dim3(512), 0, stream);
  hipLaunchKernelGGL(k4a, dim3(NK4), dim3(512), 0, stream);
  hipLaunchKernelGGL(k4b, dim3(1), dim3(512), 0, stream, wts, out);
}